// Round 3
// baseline (169.584 us; speedup 1.0000x reference)
//
#include <hip/hip_runtime.h>

#define HID 768
#define NL  17
#define BB  64
#define TT  512

// ===========================================================================
// Kernel 1: emissions = outputs @ fc_w^T + fc_b   (32768x768 @ 768x17)
// 256 threads (4 waves), 64 rows/block, K chunked by 128 through LDS.
// Wave w handles cols [32w,32w+32) of each chunk; lane = row.
// ===========================================================================
#define ROWS 64
#define XCH  128
#define NCH  (HID / XCH)     // 6
#define LROW 132             // padded row (floats); 33 granules -> stride-1 bank pattern

__global__ __launch_bounds__(256) void emis_kernel(const float* __restrict__ x,
                                                   const float* __restrict__ w,
                                                   const float* __restrict__ bias,
                                                   float* __restrict__ y) {
    __shared__ float xs[ROWS * LROW];          // 33.8 KB
    __shared__ float pacc[4][NL][65];          // 17.7 KB

    const int tid  = threadIdx.x;
    const int lane = tid & 63;
    const int wid  = __builtin_amdgcn_readfirstlane(tid >> 6);  // force SGPR -> scalar w loads
    const size_t rowbase = (size_t)blockIdx.x * ROWS;

    const int sr = tid >> 5;                   // staging row (0..7, step 8)
    const int sc = (tid & 31) << 2;            // staging col (floats)

    float acc[NL];
#pragma unroll
    for (int k = 0; k < NL; ++k) acc[k] = 0.f;

    for (int c = 0; c < NCH; ++c) {
        // ---- stage chunk c: global (coalesced) -> regs -> LDS ----
        float4 st[8];
#pragma unroll
        for (int i = 0; i < 8; ++i)
            st[i] = *reinterpret_cast<const float4*>(
                x + (rowbase + sr + i * 8) * HID + c * XCH + sc);
        __syncthreads();                       // previous chunk's readers done
#pragma unroll
        for (int i = 0; i < 8; ++i)
            *reinterpret_cast<float4*>(&xs[(sr + i * 8) * LROW + sc]) = st[i];
        __syncthreads();

        // ---- compute: lane = row, 32 cols per wave ----
        float4 xf[8];
#pragma unroll
        for (int u = 0; u < 8; ++u)
            xf[u] = *reinterpret_cast<const float4*>(&xs[lane * LROW + wid * 32 + u * 4]);
#pragma unroll
        for (int k = 0; k < NL; ++k) {
            const float* wp = w + k * HID + c * XCH + wid * 32;   // wave-uniform -> s_load
            float s0 = 0.f, s1 = 0.f, s2 = 0.f, s3 = 0.f;
#pragma unroll
            for (int u = 0; u < 8; ++u) {
                const float4 wv = *reinterpret_cast<const float4*>(wp + u * 4);
                s0 = fmaf(xf[u].x, wv.x, s0);
                s1 = fmaf(xf[u].y, wv.y, s1);
                s2 = fmaf(xf[u].z, wv.z, s2);
                s3 = fmaf(xf[u].w, wv.w, s3);
            }
            acc[k] += (s0 + s1) + (s2 + s3);
        }
    }

#pragma unroll
    for (int k = 0; k < NL; ++k) pacc[wid][k][lane] = acc[k];
    __syncthreads();

    for (int o = tid; o < ROWS * NL; o += 256) {
        const int r = o / NL, k = o % NL;
        float s = bias[k];
#pragma unroll
        for (int sp = 0; sp < 4; ++sp) s += pacc[sp][k][r];
        y[rowbase * NL + o] = s;
    }
}

// ===========================================================================
// Kernel 2: CRF llh. 1 wave per batch. Exp-domain scan, eem pre-exp'd into
// LDS transposed [17][524] so each lane streams its column via float4,
// prefetched one 8-step group ahead. Renorm by p0 every 8 steps.
// ===========================================================================
__device__ __forceinline__ float bcast(float v, int i) {
    return __uint_as_float(__builtin_amdgcn_readlane(__float_as_uint(v), i));
}

#define EXROW 524

#define CRF_BODY(eem, PN)  \
    { float q0, q1, q2, q3;                                               \
      q0 = bcast(p,  0) * et0;  q1 = bcast(p,  1) * et1;                  \
      q2 = bcast(p,  2) * et2;  q3 = bcast(p,  3) * et3;                  \
      q0 = fmaf(bcast(p,  4), et4,  q0); q1 = fmaf(bcast(p,  5), et5,  q1); \
      q2 = fmaf(bcast(p,  6), et6,  q2); q3 = fmaf(bcast(p,  7), et7,  q3); \
      q0 = fmaf(bcast(p,  8), et8,  q0); q1 = fmaf(bcast(p,  9), et9,  q1); \
      q2 = fmaf(bcast(p, 10), et10, q2); q3 = fmaf(bcast(p, 11), et11, q3); \
      q0 = fmaf(bcast(p, 12), et12, q0); q1 = fmaf(bcast(p, 13), et13, q1); \
      q2 = fmaf(bcast(p, 14), et14, q2); q3 = fmaf(bcast(p, 15), et15, q3); \
      q0 = fmaf(bcast(p, 16), et16, q0);                                  \
      PN = ((q0 + q1) + (q2 + q3)) * (eem); }

#define CRF_STEP(eem)        { float pn_; CRF_BODY(eem, pn_); p = pn_; }
#define CRF_STEPG(eem, tt)   { float pn_; CRF_BODY(eem, pn_); p = ((tt) < len) ? pn_ : p; }

__global__ __launch_bounds__(64) void crf_kernel(const float* __restrict__ emis,
                                                 const float* __restrict__ st_,
                                                 const float* __restrict__ en_,
                                                 const float* __restrict__ tr_,
                                                 const int* __restrict__ labels,
                                                 const int* __restrict__ mask,
                                                 float* __restrict__ llh) {
    __shared__ float ex[NL][EXROW];            // exp(em) transposed, 35.6 KB
    __shared__ float trs[NL * NL];

    const int b = blockIdx.x;
    const int l = threadIdx.x;

    // sequence length (prefix mask)
    int lenp = 0;
    for (int i = l; i < TT; i += 64) lenp += (mask[b * TT + i] != 0);
#pragma unroll
    for (int off = 32; off; off >>= 1) lenp += __shfl_down(lenp, off);
    const int len = __shfl(lenp, 0);

    for (int i = l; i < NL * NL; i += 64) trs[i] = tr_[i];

    // stage exp(emissions) transposed (only t < len needed)
    const float* eb = emis + (size_t)b * TT * NL;
    const int n = len * NL;
    for (int i = l; i < n; i += 64) {
        const int t = i / NL, j = i - t * NL;
        ex[j][t] = __expf(eb[i]);
    }
    __syncthreads();

    // ---------------- numerator (raw values from global) ----------------
    float np = 0.f;
    for (int t = l; t < len; t += 64) {
        int tag = labels[b * TT + t];
        if ((unsigned)tag >= NL) tag = 0;
        if (t == 0) {
            np += st_[tag] + eb[tag];
        } else {
            int tp = labels[b * TT + t - 1];
            if ((unsigned)tp >= NL) tp = 0;
            np += trs[tp * NL + tag] + eb[t * NL + tag];
        }
        if (t == len - 1) np += en_[tag];
    }
#pragma unroll
    for (int off = 32; off; off >>= 1) np += __shfl_down(np, off);
    const float num = __shfl(np, 0);

    // ---------------- denominator: exp-domain forward scan ----------------
    const bool act = (l < NL);
    const int  j   = act ? l : 0;

    const float et0  = act ? __expf(trs[ 0 * NL + j]) : 0.f;
    const float et1  = act ? __expf(trs[ 1 * NL + j]) : 0.f;
    const float et2  = act ? __expf(trs[ 2 * NL + j]) : 0.f;
    const float et3  = act ? __expf(trs[ 3 * NL + j]) : 0.f;
    const float et4  = act ? __expf(trs[ 4 * NL + j]) : 0.f;
    const float et5  = act ? __expf(trs[ 5 * NL + j]) : 0.f;
    const float et6  = act ? __expf(trs[ 6 * NL + j]) : 0.f;
    const float et7  = act ? __expf(trs[ 7 * NL + j]) : 0.f;
    const float et8  = act ? __expf(trs[ 8 * NL + j]) : 0.f;
    const float et9  = act ? __expf(trs[ 9 * NL + j]) : 0.f;
    const float et10 = act ? __expf(trs[10 * NL + j]) : 0.f;
    const float et11 = act ? __expf(trs[11 * NL + j]) : 0.f;
    const float et12 = act ? __expf(trs[12 * NL + j]) : 0.f;
    const float et13 = act ? __expf(trs[13 * NL + j]) : 0.f;
    const float et14 = act ? __expf(trs[14 * NL + j]) : 0.f;
    const float et15 = act ? __expf(trs[15 * NL + j]) : 0.f;
    const float et16 = act ? __expf(trs[16 * NL + j]) : 0.f;

    const float4 e0 = *reinterpret_cast<const float4*>(&ex[j][0]);
    float p = act ? __expf(st_[j]) * e0.x : 0.f;
    float M = 0.f;

    // prologue t = 1..3 (len >= 128 always, but guard anyway)
    if (1 < len) CRF_STEP(e0.y);
    if (2 < len) CRF_STEP(e0.z);
    if (3 < len) CRF_STEP(e0.w);

    // main loop: 8 steps/iter, loads prefetched one iteration ahead
    float4 pf0 = *reinterpret_cast<const float4*>(&ex[j][4]);
    float4 pf1 = *reinterpret_cast<const float4*>(&ex[j][8]);
    for (int t0 = 4; t0 < len; t0 += 8) {
        const float4 cA = pf0, cB = pf1;
        pf0 = *reinterpret_cast<const float4*>(&ex[j][t0 + 8]);
        pf1 = *reinterpret_cast<const float4*>(&ex[j][t0 + 12]);
        if (t0 + 8 <= len) {
            CRF_STEP(cA.x); CRF_STEP(cA.y); CRF_STEP(cA.z); CRF_STEP(cA.w);
            CRF_STEP(cB.x); CRF_STEP(cB.y); CRF_STEP(cB.z); CRF_STEP(cB.w);
        } else {
            CRF_STEPG(cA.x, t0 + 0); CRF_STEPG(cA.y, t0 + 1);
            CRF_STEPG(cA.z, t0 + 2); CRF_STEPG(cA.w, t0 + 3);
            CRF_STEPG(cB.x, t0 + 4); CRF_STEPG(cB.y, t0 + 5);
            CRF_STEPG(cB.z, t0 + 6); CRF_STEPG(cB.w, t0 + 7);
        }
        const float p0 = bcast(p, 0);          // renorm every 8 steps
        M += __logf(p0);
        p *= __frcp_rn(p0);
    }

    float v = act ? p * __expf(en_[j]) : 0.f;
#pragma unroll
    for (int off = 32; off; off >>= 1) v += __shfl_down(v, off);

    if (l == 0) llh[b] = num - (M + __logf(v));
}

// ===========================================================================
// Kernel 3: loss = -mean(llh)
// ===========================================================================
__global__ __launch_bounds__(64) void loss_kernel(const float* __restrict__ llh,
                                                  float* __restrict__ loss) {
    float v = llh[threadIdx.x];
#pragma unroll
    for (int off = 32; off; off >>= 1) v += __shfl_down(v, off);
    if (threadIdx.x == 0) loss[0] = -(v * (1.0f / BB));
}

// ===========================================================================
extern "C" void kernel_launch(void* const* d_in, const int* in_sizes, int n_in,
                              void* d_out, int out_size, void* d_ws, size_t ws_size,
                              hipStream_t stream) {
    const float* outputs = (const float*)d_in[0];
    const float* fc_w    = (const float*)d_in[1];
    const float* fc_b    = (const float*)d_in[2];
    const float* start_t = (const float*)d_in[3];
    const float* end_t   = (const float*)d_in[4];
    const float* trans   = (const float*)d_in[5];
    const int*   labels  = (const int*)d_in[6];
    const int*   mask    = (const int*)d_in[7];

    float* emis = (float*)d_out;
    float* loss = emis + (size_t)BB * TT * NL;
    float* llh  = (float*)d_ws;

    emis_kernel<<<(BB * TT) / ROWS, 256, 0, stream>>>(outputs, fc_w, fc_b, emis);
    crf_kernel<<<BB, 64, 0, stream>>>(emis, start_t, end_t, trans, labels, mask, llh);
    loss_kernel<<<1, 64, 0, stream>>>(llh, loss);
}